// Round 11
// baseline (27897.968 us; speedup 1.0000x reference)
//
#include <hip/hip_runtime.h>
#include <hip/hip_bf16.h>
#include <math.h>

// RSSM scan — numpy-realization f32 (frozen numerics), r11: single persistent
// mega-kernel, 512 co-resident blocks, device-wide sense barriers replace the
// 8 per-step launches (launch-gap was ~95us/step of the 174us step time).
// All per-thread numeric bodies verbatim from passing r10.

#define NB 512
constexpr int KS = 1 << 30;

struct GArg {
  const float* A0; int lda0;
  const float* A1; int lda1;
  int kSplit;
  const float* W; int ldw;
  float* C; int N; int K;             // panel s written at C + s*256*N
};

__device__ __forceinline__ float exp_cr(float x)  { return (float)exp((double)x); }
__device__ __forceinline__ float log_cr(float x)  { return (float)log((double)x); }
__device__ __forceinline__ float tanh_cr(float x) { return (float)tanh((double)x); }
__device__ __forceinline__ float sigmoid_cr(float x) {
  float e = exp_cr(-x);
  float d = __fadd_rn(1.0f, e);
  return __fdiv_rn(1.0f, d);
}

// ---- device-wide barrier: monotone count + generation flag ----
__device__ __forceinline__ void gbar(unsigned* cnt, unsigned* gen, unsigned* round) {
  __syncthreads();                      // all block stores retired (vmcnt 0)
  if (threadIdx.x == 0) {
    unsigned target = ++(*round);
    __threadfence();                    // release: wb this XCD's L2
    unsigned v = atomicAdd(cnt, 1u);
    if (v == target * (unsigned)NB - 1u) atomicAdd(gen, 1u);
    while (__hip_atomic_load(gen, __ATOMIC_RELAXED, __HIP_MEMORY_SCOPE_AGENT) < target)
      __builtin_amdgcn_s_sleep(2);
    __threadfence();                    // acquire: inv L1/L2
  }
  __syncthreads();
}

// ---- one 64x64x(384-panel) tile; body verbatim r10 (entry sync added) ----
__device__ void gemm_tile(const GArg& G, int s, int n0, int m0,
                          float (*As)[16][68], float (*Bs)[16][68])
{
  int tid = threadIdx.x;
  int tx = tid & 15, ty = tid >> 4;
  int kq = tid & 3,  rr = tid >> 2;

  bool vecOK = ((G.ldw & 3) == 0) && ((G.lda0 & 3) == 0) && ((G.lda1 & 3) == 0)
            && (((G.kSplit & 15) == 0) || (G.kSplit >= G.K));

  float acc[4][4];
  #pragma unroll
  for (int j = 0; j < 4; ++j)
    #pragma unroll
    for (int i = 0; i < 4; ++i) acc[j][i] = 0.0f;

  int nt = (G.K + 15) >> 4;
  int t0 = s * 24, t1 = min(nt, t0 + 24);

  float a[4], w[4];
  int useVec = 0;

  auto stage_load = [&](int kt) {
    int kb = kt * 16;
    useVec = vecOK && (kb + 16 <= G.K);
    if (useVec) {
      int k = kb + kq * 4;
      float4 av = (k < G.kSplit)
        ? *(const float4*)(G.A0 + (size_t)(m0 + rr) * G.lda0 + k)
        : *(const float4*)(G.A1 + (size_t)(m0 + rr) * G.lda1 + (k - G.kSplit));
      float4 wv = *(const float4*)(G.W + (size_t)(n0 + rr) * G.ldw + k);
      a[0] = av.x; a[1] = av.y; a[2] = av.z; a[3] = av.w;
      w[0] = wv.x; w[1] = wv.y; w[2] = wv.z; w[3] = wv.w;
    } else {
      int k = kb + tx;
      #pragma unroll
      for (int i = 0; i < 4; ++i) { a[i] = 0.0f; w[i] = 0.0f; }
      if (k < G.K) {
        if (k < G.kSplit) {
          const float* Ap = G.A0 + (size_t)(m0 + ty * 4) * G.lda0 + k;
          #pragma unroll
          for (int i = 0; i < 4; ++i) a[i] = Ap[(size_t)i * G.lda0];
        } else {
          const float* Ap = G.A1 + (size_t)(m0 + ty * 4) * G.lda1 + (k - G.kSplit);
          #pragma unroll
          for (int i = 0; i < 4; ++i) a[i] = Ap[(size_t)i * G.lda1];
        }
        const float* Wp = G.W + (size_t)(n0 + ty * 4) * G.ldw + k;
        #pragma unroll
        for (int i = 0; i < 4; ++i) w[i] = Wp[(size_t)i * G.ldw];
      }
    }
  };
  auto stage_write = [&](int b) {
    if (useVec) {
      #pragma unroll
      for (int i = 0; i < 4; ++i) {
        As[b][kq * 4 + i][rr] = a[i];
        Bs[b][kq * 4 + i][rr] = w[i];
      }
    } else {
      *(float4*)&As[b][tx][ty * 4] = make_float4(a[0], a[1], a[2], a[3]);
      *(float4*)&Bs[b][tx][ty * 4] = make_float4(w[0], w[1], w[2], w[3]);
    }
  };
  auto compute = [&](int b) {
    #pragma unroll
    for (int kk = 0; kk < 16; ++kk) {
      float4 av = *(const float4*)&As[b][kk][ty * 4];
      float4 bv = *(const float4*)&Bs[b][kk][tx * 4];
      float aa[4] = {av.x, av.y, av.z, av.w};
      float bb[4] = {bv.x, bv.y, bv.z, bv.w};
      #pragma unroll
      for (int j = 0; j < 4; ++j)
        #pragma unroll
        for (int i = 0; i < 4; ++i)
          acc[j][i] = fmaf(aa[j], bb[i], acc[j][i]);   // k-ascending chain
    }
  };

  __syncthreads();                       // previous tile's LDS readers done
  stage_load(t0); stage_write(0); __syncthreads();
  int cur = 0;
  for (int kt = t0; kt < t1; ++kt) {
    if (kt + 1 < t1) {
      stage_load(kt + 1);
      compute(cur);
      stage_write(cur ^ 1);
      __syncthreads();
      cur ^= 1;
    } else compute(cur);
  }

  float* Cp = G.C + (size_t)s * 256 * G.N;
  #pragma unroll
  for (int j = 0; j < 4; ++j)
    *(float4*)&Cp[(size_t)(m0 + ty * 4 + j) * G.N + n0 + tx * 4] =
      make_float4(acc[j][0], acc[j][1], acc[j][2], acc[j][3]);
}

// grid-stride over up to 3 GArgs' tiles
__device__ void run3(const GArg& A, int ca, const GArg& B, int cb,
                     const GArg& C, int cc,
                     float (*As)[16][68], float (*Bs)[16][68])
{
  int tot = ca + cb + cc;
  for (int wv = blockIdx.x; wv < tot; wv += NB) {
    const GArg* G; int l;
    if (wv < ca)            { G = &A; l = wv; }
    else if (wv < ca + cb)  { G = &B; l = wv - ca; }
    else                    { G = &C; l = wv - ca - cb; }
    int nbx = G->N >> 6;
    int per = nbx * 4;
    int s = l / per, rem = l % per;
    int mb = rem / nbx, nb = rem % nbx;
    gemm_tile(*G, s, nb * 64, mb * 64, As, Bs);
  }
}

// ---- LN + SiLU for one row; body verbatim r10 ----
__device__ void ln_row(const float* Y, int S, const float* bias, const float* gg,
                       const float* be, float* O, int row,
                       float (*xs)[20], float* stats)
{
  int tid = threadIdx.x;
  int cl = tid & 63, iq = tid >> 6;
  int kb = cl >> 3, j = cl & 7;

  float xv[4];
  #pragma unroll
  for (int q = 0; q < 4; ++q) {
    int i = iq * 4 + q;
    int n = kb * 128 + 8 * i + j;
    size_t idx = (size_t)row * 1024 + n;
    float x = Y[idx];
    for (int ss = 1; ss < S; ++ss) x = __fadd_rn(x, Y[(size_t)ss * 262144 + idx]);
    x = __fadd_rn(x, bias[n]);
    xv[q] = x;
    xs[cl][i] = x;
  }
  __syncthreads();
  if (tid < 64) {
    float r = xs[cl][0];
    #pragma unroll
    for (int i = 1; i < 16; ++i) r = __fadd_rn(r, xs[cl][i]);
    r = __fadd_rn(r, __shfl_xor(r, 1));
    r = __fadd_rn(r, __shfl_xor(r, 2));
    r = __fadd_rn(r, __shfl_xor(r, 4));
    r = __fadd_rn(r, __shfl_xor(r, 8));
    r = __fadd_rn(r, __shfl_xor(r, 16));
    r = __fadd_rn(r, __shfl_xor(r, 32));
    float mean = __fmul_rn(r, 0.0009765625f);
    float d0 = __fsub_rn(xs[cl][0], mean);
    float r2 = __fmul_rn(d0, d0);
    #pragma unroll
    for (int i = 1; i < 16; ++i) {
      float d = __fsub_rn(xs[cl][i], mean);
      r2 = __fadd_rn(r2, __fmul_rn(d, d));
    }
    r2 = __fadd_rn(r2, __shfl_xor(r2, 1));
    r2 = __fadd_rn(r2, __shfl_xor(r2, 2));
    r2 = __fadd_rn(r2, __shfl_xor(r2, 4));
    r2 = __fadd_rn(r2, __shfl_xor(r2, 8));
    r2 = __fadd_rn(r2, __shfl_xor(r2, 16));
    r2 = __fadd_rn(r2, __shfl_xor(r2, 32));
    float var = __fmul_rn(r2, 0.0009765625f);
    float sdv = __fsqrt_rn(__fadd_rn(var, (float)1e-5));
    if (cl == 0) { stats[0] = mean; stats[1] = __fdiv_rn(1.0f, sdv); }
  }
  __syncthreads();
  float mean = stats[0], rstd = stats[1];
  #pragma unroll
  for (int q = 0; q < 4; ++q) {
    int i = iq * 4 + q;
    int n = kb * 128 + 8 * i + j;
    float d = __fsub_rn(xv[q], mean);
    float t = __fmul_rn(__fmul_rn(d, rstd), gg[n]);
    t = __fadd_rn(t, be[n]);
    O[(size_t)row * 1024 + n] = __fmul_rn(t, sigmoid_cr(t));   // silu
  }
}

// ---- GRU combine + LN for one row; body verbatim r10 ----
__device__ void gru_row(const float* GX, const float* GH, float* H,
                        const float* b_ih, const float* b_hh,
                        const float* g_gn, const float* b_gn,
                        float* out, int t, int row,
                        float (*xs)[20], float* stats)
{
  int tid = threadIdx.x;
  int cl = tid & 63, iq = tid >> 6;
  int kb = cl >> 3, j = cl & 7;

  float hv[4];
  #pragma unroll
  for (int q = 0; q < 4; ++q) {
    int i = iq * 4 + q;
    int n = kb * 128 + 8 * i + j;
    size_t i0 = (size_t)row * 3072 + n;
    #define FOLD3(P, off) __fadd_rn(__fadd_rn((P)[off], (P)[786432 + (off)]), (P)[1572864 + (off)])
    float xr = __fadd_rn(FOLD3(GX, i0),        b_ih[n]);
    float xu = __fadd_rn(FOLD3(GX, i0 + 1024), b_ih[n + 1024]);
    float xn = __fadd_rn(FOLD3(GX, i0 + 2048), b_ih[n + 2048]);
    float hr = __fadd_rn(FOLD3(GH, i0),        b_hh[n]);
    float hu = __fadd_rn(FOLD3(GH, i0 + 1024), b_hh[n + 1024]);
    float hn = __fadd_rn(FOLD3(GH, i0 + 2048), b_hh[n + 2048]);
    #undef FOLD3
    float r = sigmoid_cr(__fadd_rn(xr, hr));
    float u = sigmoid_cr(__fadd_rn(xu, hu));
    float nn = tanh_cr(__fadd_rn(xn, __fmul_rn(r, hn)));
    float h2 = __fadd_rn(__fmul_rn(__fsub_rn(1.0f, u), nn),
                         __fmul_rn(u, H[(size_t)row * 1024 + n]));
    hv[q] = h2;
    xs[cl][i] = h2;
  }
  __syncthreads();
  if (tid < 64) {
    float r = xs[cl][0];
    #pragma unroll
    for (int i = 1; i < 16; ++i) r = __fadd_rn(r, xs[cl][i]);
    r = __fadd_rn(r, __shfl_xor(r, 1));
    r = __fadd_rn(r, __shfl_xor(r, 2));
    r = __fadd_rn(r, __shfl_xor(r, 4));
    r = __fadd_rn(r, __shfl_xor(r, 8));
    r = __fadd_rn(r, __shfl_xor(r, 16));
    r = __fadd_rn(r, __shfl_xor(r, 32));
    float mean = __fmul_rn(r, 0.0009765625f);
    float d0 = __fsub_rn(xs[cl][0], mean);
    float r2 = __fmul_rn(d0, d0);
    #pragma unroll
    for (int i = 1; i < 16; ++i) {
      float d = __fsub_rn(xs[cl][i], mean);
      r2 = __fadd_rn(r2, __fmul_rn(d, d));
    }
    r2 = __fadd_rn(r2, __shfl_xor(r2, 1));
    r2 = __fadd_rn(r2, __shfl_xor(r2, 2));
    r2 = __fadd_rn(r2, __shfl_xor(r2, 4));
    r2 = __fadd_rn(r2, __shfl_xor(r2, 8));
    r2 = __fadd_rn(r2, __shfl_xor(r2, 16));
    r2 = __fadd_rn(r2, __shfl_xor(r2, 32));
    float var = __fmul_rn(r2, 0.0009765625f);
    float sdv = __fsqrt_rn(__fadd_rn(var, (float)1e-5));
    if (cl == 0) { stats[0] = mean; stats[1] = __fdiv_rn(1.0f, sdv); }
  }
  __syncthreads();
  float mean = stats[0], rstd = stats[1];
  #pragma unroll
  for (int q = 0; q < 4; ++q) {
    int i = iq * 4 + q;
    int n = kb * 128 + 8 * i + j;
    float d = __fsub_rn(hv[q], mean);
    float h3 = __fadd_rn(__fmul_rn(__fmul_rn(d, rstd), g_gn[n]), b_gn[n]);
    H[(size_t)row * 1024 + n] = h3;
    out[((size_t)row * 64 + t) * 1024 + n] = h3;
  }
}

// ---- sample row (posterior frozen / prior value-safe); body verbatim r10 ----
__device__ void sample_row(const float* Yq, const float* bq2,
                           const float* Y2p, const float* bp2,
                           const float* u_post, const float* actions,
                           float* XZ, float* out, int t, int b, int prior)
{
  const size_t NOUT = 16777216ull;
  int tid = threadIdx.x;
  int d = tid >> 3, lane = tid & 7;
  const float C0 = (float)(1.0 - 0.01);
  const float C1 = (float)(0.01 / 32.0);
  const float* Y = prior ? Y2p : Yq;
  const float* bias = prior ? bp2 : bq2;

  float lg[4];
  #pragma unroll
  for (int i = 0; i < 4; ++i) {
    int col = d * 32 + lane + 8 * i;
    size_t idx = (size_t)b * 1024 + col;
    float x = __fadd_rn(__fadd_rn(Y[idx], Y[262144 + idx]), Y[524288 + idx]);
    lg[i] = __fadd_rn(x, bias[col]);
  }
  float mx = fmaxf(fmaxf(lg[0], lg[1]), fmaxf(lg[2], lg[3]));
  for (int off = 4; off; off >>= 1) mx = fmaxf(mx, __shfl_xor(mx, off, 8));

  float e[4];
  #pragma unroll
  for (int i = 0; i < 4; ++i) e[i] = exp_cr(__fsub_rn(lg[i], mx));
  float ssum = e[0];
  ssum = __fadd_rn(ssum, e[1]);
  ssum = __fadd_rn(ssum, e[2]);
  ssum = __fadd_rn(ssum, e[3]);
  ssum = __fadd_rn(ssum, __shfl_xor(ssum, 1, 8));
  ssum = __fadd_rn(ssum, __shfl_xor(ssum, 2, 8));
  ssum = __fadd_rn(ssum, __shfl_xor(ssum, 4, 8));

  float p[4];
  #pragma unroll
  for (int i = 0; i < 4; ++i) {
    float pr = __fdiv_rn(e[i], ssum);
    p[i] = __fadd_rn(__fmul_rn(C0, pr), C1);
  }

  size_t ob = ((size_t)b * 64 + t) * 1024;
  if (prior) {
    #pragma unroll
    for (int i = 0; i < 4; ++i)
      out[2 * NOUT + ob + (d * 32 + lane + 8 * i)] = p[i];
    return;
  }

  float bv = -3.4e38f; int bc = 33;
  #pragma unroll
  for (int i = 0; i < 4; ++i) {
    int c = lane + 8 * i, col = d * 32 + c;
    out[3 * NOUT + ob + col] = p[i];
    float uu = u_post[((size_t)t * 256 + b) * 1024 + col];
    float l1 = log_cr(uu);
    float v1 = -l1;
    float l2 = log_cr(v1);
    float gu = -l2;
    float lp = log_cr(p[i]);
    float val = __fadd_rn(lp, gu);
    if (val > bv) { bv = val; bc = c; }       // first max (c ascending)
  }
  for (int off = 4; off; off >>= 1) {
    float ov = __shfl_xor(bv, off, 8);
    int   oc = __shfl_xor(bc, off, 8);
    if (ov > bv || (ov == bv && oc < bc)) { bv = ov; bc = oc; }
  }
  #pragma unroll
  for (int i = 0; i < 4; ++i) {
    int c = lane + 8 * i, col = d * 32 + c;
    float zv = 0.0f;
    if (c == bc) zv = __fsub_rn(__fadd_rn(1.0f, p[i]), p[i]);
    out[NOUT + ob + col] = zv;
    XZ[(size_t)b * 1040 + col] = zv;
  }
  if (tid < 6 && (t + 1) < 64)
    XZ[(size_t)b * 1040 + 1024 + tid] = actions[((size_t)b * 64 + (t + 1)) * 6 + tid];
}

struct MegaP {
  const float *embeds, *actions, *h_init, *z_init;
  const float *W_pre, *b_pre, *g_pre, *be_pre;
  const float *W_ih, *W_hh, *b_ih, *b_hh, *g_gn, *b_gn;
  const float *Wp1, *bp1, *gp, *bpn, *Wp2, *bp2;
  const float *Wq1, *bq1, *gq, *bqn, *Wq2, *bq2;
  const float *u_post;
  float* out;
  float *H, *XZ, *PREY, *Q1A, *GX, *GH, *YQ, *Y2p, *YQ2, *XPRE, *Y1p, *P1Ap;
  unsigned *cnt, *gen;
};

__global__ void bar_init_k(unsigned* base) { base[0] = 0; base[32] = 0; }

__global__ __launch_bounds__(256, 2) void mega_k(MegaP P)
{
  __shared__ float As[2][16][68];
  __shared__ float Bs[2][16][68];
  __shared__ float xs[64][20];
  __shared__ float stats[2];
  unsigned round = 0;

  // init H, XZ
  for (int r = blockIdx.x; r < 256; r += NB) {
    int tid = threadIdx.x;
    #pragma unroll
    for (int j = 0; j < 4; ++j) {
      int n = tid + j * 256;
      P.H [(size_t)r * 1024 + n] = P.h_init[(size_t)r * 1024 + n];
      P.XZ[(size_t)r * 1040 + n] = P.z_init[(size_t)r * 1024 + n];
    }
    if (tid < 6) P.XZ[(size_t)r * 1040 + 1024 + tid] = P.actions[(size_t)r * 64 * 6 + tid];
  }
  gbar(P.cnt, P.gen, &round);

  GArg dummy{nullptr, 0, nullptr, 0, 0, nullptr, 0, nullptr, 0, 0};

  for (int t = 0; t < 64; ++t) {
    // A: pre(t): PREY = panels([z|a] @ W_pre^T), K=1030 (scalar staging path)
    {
      GArg pre{P.XZ, 1040, P.XZ, 1040, KS, P.W_pre, 1030, P.PREY, 1024, 1030};
      run3(pre, 192, dummy, 0, dummy, 0, As, Bs);
    }
    gbar(P.cnt, P.gen, &round);
    // B: lnpre -> XPRE
    for (int r = blockIdx.x; r < 256; r += NB)
      ln_row(P.PREY, 3, P.b_pre, P.g_pre, P.be_pre, P.XPRE, r, xs, stats);
    gbar(P.cnt, P.gen, &round);
    // C: GX(t) [+ GH(0) at t=0]
    {
      GArg gx{P.XPRE, 1024, P.XPRE, 1024, KS, P.W_ih, 1024, P.GX, 3072, 1024};
      GArg gh{P.H,    1024, P.H,    1024, KS, P.W_hh, 1024, P.GH, 3072, 1024};
      if (t == 0) run3(gx, 576, gh, 576, dummy, 0, As, Bs);
      else        run3(gx, 576, dummy, 0, dummy, 0, As, Bs);
    }
    gbar(P.cnt, P.gen, &round);
    // D: gru -> H, hs
    for (int r = blockIdx.x; r < 256; r += NB)
      gru_row(P.GX, P.GH, P.H, P.b_ih, P.b_hh, P.g_gn, P.b_gn, P.out, t, r, xs, stats);
    gbar(P.cnt, P.gen, &round);
    // E: q1(t) + GH(t+1) + py1(t)
    {
      GArg q1 {P.H, 1024, P.embeds + (size_t)t * 1024, 65536, 1024,
               P.Wq1, 2048, P.YQ, 1024, 2048};
      GArg gh {P.H, 1024, P.H, 1024, KS, P.W_hh, 1024, P.GH, 3072, 1024};
      GArg py1{P.out + (size_t)t * 1024, 65536, P.out, 65536, KS,
               P.Wp1, 1024, P.Y1p, 1024, 1024};
      if (t < 63) run3(q1, 384, gh, 576, py1, 192, As, Bs);
      else        run3(q1, 384, py1, 192, dummy, 0, As, Bs);
    }
    gbar(P.cnt, P.gen, &round);
    // F: lnq -> Q1A ; priorLN -> P1Ap
    for (int r = blockIdx.x; r < 512; r += NB) {
      if (r < 256) ln_row(P.YQ, 6, P.bq1, P.gq, P.bqn, P.Q1A, r, xs, stats);
      else         ln_row(P.Y1p, 3, P.bp1, P.gp, P.bpn, P.P1Ap, r - 256, xs, stats);
    }
    gbar(P.cnt, P.gen, &round);
    // G: q2(t) + py2(t)
    {
      GArg q2 {P.Q1A,  1024, P.Q1A,  1024, KS, P.Wq2, 1024, P.YQ2, 1024, 1024};
      GArg py2{P.P1Ap, 1024, P.P1Ap, 1024, KS, P.Wp2, 1024, P.Y2p, 1024, 1024};
      run3(q2, 192, py2, 192, dummy, 0, As, Bs);
    }
    gbar(P.cnt, P.gen, &round);
    // H: posterior sample + prior softmax
    for (int r = blockIdx.x; r < 512; r += NB)
      sample_row(P.YQ2, P.bq2, P.Y2p, P.bp2, P.u_post, P.actions,
                 P.XZ, P.out, t, r & 255, r >> 8);
    gbar(P.cnt, P.gen, &round);
  }
}

extern "C" void kernel_launch(void* const* d_in, const int* in_sizes, int n_in,
                              void* d_out, int out_size, void* d_ws, size_t ws_size,
                              hipStream_t stream)
{
  MegaP P;
  P.embeds  = (const float*)d_in[0];
  P.actions = (const float*)d_in[1];
  P.h_init  = (const float*)d_in[2];
  P.z_init  = (const float*)d_in[3];
  P.W_pre   = (const float*)d_in[4];
  P.b_pre   = (const float*)d_in[5];
  P.g_pre   = (const float*)d_in[6];
  P.be_pre  = (const float*)d_in[7];
  P.W_ih    = (const float*)d_in[8];
  P.W_hh    = (const float*)d_in[9];
  P.b_ih    = (const float*)d_in[10];
  P.b_hh    = (const float*)d_in[11];
  P.g_gn    = (const float*)d_in[12];
  P.b_gn    = (const float*)d_in[13];
  P.Wp1     = (const float*)d_in[14];
  P.bp1     = (const float*)d_in[15];
  P.gp      = (const float*)d_in[16];
  P.bpn     = (const float*)d_in[17];
  P.Wp2     = (const float*)d_in[18];
  P.bp2     = (const float*)d_in[19];
  P.Wq1     = (const float*)d_in[20];
  P.bq1     = (const float*)d_in[21];
  P.gq      = (const float*)d_in[22];
  P.bqn     = (const float*)d_in[23];
  P.Wq2     = (const float*)d_in[24];
  P.bq2     = (const float*)d_in[25];
  // d_in[26] = u_prior: unused
  P.u_post  = (const float*)d_in[27];
  P.out     = (float*)d_out;

  // workspace layout (floats) — same as passing r10, + barrier words at tail
  float* W0 = (float*)d_ws;
  P.H    = W0;                    // 262144
  P.XZ   = W0 + 262144;           // 266240 (row stride 1040)
  P.PREY = W0 + 528384;           // 786432 (3 panels); alias Q1A
  P.Q1A  = P.PREY;                //   Q1A: wr F, rd G; PREY: wr A(t+1), rd B
  P.GX   = W0 + 1314816;          // 2359296 (3 panels)
  P.GH   = W0 + 3674112;          // 2359296 (3 panels; lives across step)
  P.YQ   = W0 + 6033408;          // 1572864 (6 panels); alias Y2p
  P.Y2p  = P.YQ;                  //   YQ: wr E, rd F; Y2p: wr G, rd H
  P.YQ2  = W0 + 7606272;          // 786432 (3 panels); alias XPRE
  P.XPRE = P.YQ2;                 //   YQ2: wr G, rd H; XPRE: wr B, rd C
  P.Y1p  = W0 + 8392704;          // 786432 (3 panels)
  P.P1Ap = W0 + 9179136;          // 262144
  unsigned* bar_base = (unsigned*)(W0 + 9441280);
  P.cnt = bar_base;               // [0]
  P.gen = bar_base + 32;          // [32] — separate 128B line

  hipLaunchKernelGGL(bar_init_k, dim3(1), dim3(1), 0, stream, bar_base);
  hipLaunchKernelGGL(mega_k, dim3(NB), dim3(256), 0, stream, P);
}